// Round 23
// baseline (60.870 us; speedup 1.0000x reference)
//
#include <hip/hip_runtime.h>

// Problem constants
#define BATCH 1024
#define RR    49        // 7*7 spatial
#define SP    12544     // 256*49 per-batch patch elems; also FLAT
#define KVALID 625      // nonzero correlation outputs per batch
#define KPAD   640      // padded K for GEMM1
#define REP_N  1024

typedef __attribute__((ext_vector_type(4))) float f32x4;
typedef __attribute__((ext_vector_type(8))) short s16x8;   // 8 bf16 (4 VGPRs)

// ---- bf16 split helpers (RNE) ----
__device__ __forceinline__ unsigned short f2bf_rne(float f) {
    unsigned int u = __float_as_uint(f);
    unsigned int r = u + 0x7FFFu + ((u >> 16) & 1u);
    return (unsigned short)(r >> 16);
}
__device__ __forceinline__ float bf2f(unsigned short h) {
    return __uint_as_float(((unsigned int)h) << 16);
}
__device__ __forceinline__ void split2(float v, unsigned short& h, unsigned short& l) {
    h = f2bf_rne(v);
    l = f2bf_rne(v - bf2f(h));
}
// Pack two floats to bf16 pair (verified numerically R4-R22).
__device__ __forceinline__ unsigned int cvtpk_bf16(float a, float b) {
    unsigned int r;
    asm("v_cvt_pk_bf16_f32 %0, %1, %2" : "=v"(r) : "v"(a), "v"(b));
    return r;
}
// Split 8 floats -> hi/lo s16x8 fragments.
__device__ __forceinline__ void cvt8(const float* v, s16x8& hv, s16x8& lv) {
    unsigned int* hp = (unsigned int*)&hv;
    unsigned int* lp = (unsigned int*)&lv;
    #pragma unroll
    for (int i = 0; i < 4; ++i) {
        float v0 = v[2 * i], v1 = v[2 * i + 1];
        unsigned int ph = cvtpk_bf16(v0, v1);
        float h0 = __uint_as_float(ph << 16);
        float h1 = __uint_as_float(ph & 0xFFFF0000u);
        unsigned int pl = cvtpk_bf16(v0 - h0, v1 - h1);
        hp[i] = ph; lp[i] = pl;
    }
}

// Decode index u in [0,25) -> (i, d), i,d in [0,7), i+d even.
__device__ __forceinline__ void dec25(int u, int& i, int& d) {
    int ii = (u >= 4) + (u >= 7) + (u >= 11) + (u >= 14) + (u >= 18) + (u >= 21);
    int cum = (7 * ii + 1) >> 1;
    i = ii;
    d = 2 * (u - cum) + (ii & 1);
}
// Encode (i,d) -> [0,25), inverse of dec25.
__device__ __forceinline__ int enc25(int i, int d) {
    return ((7 * i + 1) >> 1) + ((d - (i & 1)) >> 1);
}

// Compact index a in [0,640) -> flat column into W1's FLAT dim (a>=625 unused).
__device__ __forceinline__ int kflat_of(int a) {
    int ar = a / 25, ac = a % 25;
    int i, dy, j, dx;
    dec25(ar, i, dy);
    dec25(ac, j, dx);
    int pi = (dy + 16 - i) >> 1;
    int pj = (dx + 16 - j) >> 1;
    return (pi * 16 + pj) * 49 + i * 7 + j;
}

#define MM(d, a, b) d = __builtin_amdgcn_mfma_f32_16x16x32_bf16(a, b, d, 0, 0, 0)

// ---------------------------------------------------------------------------
// MEGA kernel: corr (parity Gram, verified R9/R12) + W1/W2 prep fused.
// Block routing (interleaved): bid<2048 even -> corr batch bid/2; odd ->
// W1-prep bid/2; bid>=2048 -> prep 1024+(bid-2048).
// corr: 8 half-chunks (32 ch) double-buffered via global_load_lds width=16,
// counted vmcnt (T4). CHANGE vs R21/R22: the tail load's base shifts from
// 384 to 328 (overlapping bq5 on [328,384) with IDENTICAL identity-copy
// data — benign race) instead of src-clamping into a pad. LDS 28 -> 24.5 KB
// => 6 blocks/CU.
// ---------------------------------------------------------------------------
__global__ __launch_bounds__(256) void corr_prep_kernel(
    const float* __restrict__ p1, const float* __restrict__ p2,
    const float* __restrict__ W1, const float* __restrict__ W2,
    unsigned short* __restrict__ xh, unsigned short* __restrict__ xl,
    unsigned short* __restrict__ w1h, unsigned short* __restrict__ w1l,
    unsigned short* __restrict__ w2h, unsigned short* __restrict__ w2l)
{
    __shared__ float4 Tb[2][2][392];       // [buf][tensor][392 f4] = 24.5 KB

    const int bid = blockIdx.x;
    const int t   = threadIdx.x;

    bool isCorr = false;
    int cid = 0, pid = 0;
    if (bid < 2048) {
        if ((bid & 1) == 0) { isCorr = true; cid = bid >> 1; }
        else                { pid = bid >> 1; }
    } else {
        pid = 1024 + (bid - 2048);
    }

    if (!isCorr) {
        // ---- weight prep branch (block-uniform) ----
        if (pid < 2560) {
            int idx = pid * 256 + t;             // over REP_N*KPAD
            int n = idx / KPAD, a = idx - n * KPAD;
            float v = 0.f;
            if (a < KVALID) v = W1[(size_t)n * SP + kflat_of(a)];
            unsigned short h, l;
            split2(v, h, l);
            w1h[idx] = h; w1l[idx] = l;
        } else {
            int idx = ((pid - 2560) * 256 + t) * 4;   // over REP_N*REP_N
            float4 v = *(const float4*)&W2[idx];
            unsigned short h0, l0, h1, l1, h2, l2, h3, l3;
            split2(v.x, h0, l0); split2(v.y, h1, l1);
            split2(v.z, h2, l2); split2(v.w, h3, l3);
            *(ushort4*)&w2h[idx] = make_ushort4(h0, h1, h2, h3);
            *(ushort4*)&w2l[idx] = make_ushort4(l0, l1, l2, l3);
        }
        return;
    }

    // ---- corr branch ----
    const float* P1 = p1 + (size_t)cid * SP;
    const float* P2 = p2 + (size_t)cid * SP;

    const int wv   = t >> 6;
    const int lane = t & 63;
    const int fr   = lane & 15;        // class-pos index (A row / B col)
    const int fg   = (lane >> 4) * 8;  // k-offset within 32-row tile

    // parity-class geometry
    const int ci = wv >> 1, cj = wv & 1;
    const int nj = 4 - cj;
    const int clsN = (4 - ci) * nj;          // 16 / 12 / 12 / 9
    const int pr = (fr < clsN) ? fr : 0;
    const int sPos = (2 * (pr / nj) + ci) * 7 + (2 * (pr % nj) + cj);

    // staging role: waves 0,1 -> p1; waves 2,3 -> p2. Half-chunk = 32ch*49
    // = 1568 floats = 392 float4. Even staging waves: 4 loads at bases
    // 0/64/128/192. Odd waves: 3 loads at bases 256/320/328 — the 328 load
    // overlaps [328,384) with the 320 load, writing identical data (identity
    // copy), covering the 392-f4 chunk exactly with no pad. vmcnt PER-WAVE.
    const float* PS = (wv < 2) ? P1 : P2;
    const int tens  = wv >> 1;
    const int nb    = (wv & 1) ? 3 : 4;      // loads per stage (wave-uniform)

    #define STAGE(buf, hc)                                                     \
        do {                                                                   \
            const int off_ = (hc) * 1568;                                      \
            float4* T_ = &Tb[(buf)][tens][0];                                  \
            _Pragma("unroll")                                                  \
            for (int j_ = 0; j_ < 4; ++j_) {                                   \
                if (j_ < nb) {                                                 \
                    const int base_ = (wv & 1)                                 \
                        ? ((j_ == 2) ? 328 : 256 + j_ * 64)                    \
                        : j_ * 64;                                             \
                    __builtin_amdgcn_global_load_lds(                          \
                        (const __attribute__((address_space(1))) unsigned int*)\
                            (PS + off_ + (base_ + lane) * 4),                  \
                        (__attribute__((address_space(3))) unsigned int*)      \
                            (T_ + base_),                                      \
                        16, 0, 0);                                             \
                }                                                              \
            }                                                                  \
        } while (0)

    STAGE(0, 0);   // prologue: 2 stages in flight (8 or 6 loads per wave)
    STAGE(1, 1);

    f32x4 acc = {};
    #pragma unroll
    for (int hc = 0; hc < 8; ++hc) {
        // Wait ONLY for the current stage's loads (oldest in the queue);
        // the next stage's loads remain outstanding across the barrier.
        if (hc < 7) {
            if (wv & 1) asm volatile("s_waitcnt vmcnt(3)" ::: "memory");
            else        asm volatile("s_waitcnt vmcnt(4)" ::: "memory");
        } else {
            asm volatile("s_waitcnt vmcnt(0)" ::: "memory");
        }
        __builtin_amdgcn_s_barrier();          // all waves' current loads landed
        __builtin_amdgcn_sched_barrier(0);     // pin: no ds_read hoisted above

        const int cur = hc & 1;
        const float* Tf1 = (const float*)&Tb[cur][0][0];
        const float* Tf2 = (const float*)&Tb[cur][1][0];
        const int kb = fg * RR + sPos;
        float av[8], bv[8];
        #pragma unroll
        for (int i = 0; i < 8; ++i) {
            av[i] = Tf1[kb + i * RR];
            bv[i] = Tf2[kb + i * RR];
        }
        s16x8 ah, al, bh, bl;
        cvt8(av, ah, al);
        cvt8(bv, bh, bl);
        MM(acc, ah, bh);
        MM(acc, ah, bl);
        MM(acc, al, bh);

        __builtin_amdgcn_sched_barrier(0);
        __builtin_amdgcn_s_barrier();          // all waves done reading buf[cur]
        if (hc < 6) STAGE(cur, hc + 2);        // refill the buffer just freed
    }
    #undef STAGE

    // Epilogue (verified R9 mapping): direct scattered global stores.
    // C/D layout: col = lane&15, row = 4*(lane>>4)+r.
    unsigned short* rh = xh + (size_t)cid * KPAD;
    unsigned short* rl = xl + (size_t)cid * KPAD;
    if (t < KPAD - KVALID) {                   // zero the 15-element pad tail
        rh[KVALID + t] = 0;
        rl[KVALID + t] = 0;
    }
    const int arow = (lane >> 4) * 4;
    if (fr < clsN) {
        const int dy = 2 * (fr / nj) + ci;
        const int dx = 2 * (fr % nj) + cj;
        #pragma unroll
        for (int r = 0; r < 4; ++r) {
            const int rowp = arow + r;
            if (rowp < clsN) {
                const int i1 = 2 * (rowp / nj) + ci;
                const int j1 = 2 * (rowp % nj) + cj;
                const int aidx = enc25(i1, dy) * 25 + enc25(j1, dx);
                unsigned short hh, ll;
                split2(acc[r], hh, ll);
                rh[aidx] = hh; rl[aidx] = ll;
            }
        }
    }
}

// ---------------------------------------------------------------------------
// MFMA GEMM: Y[m,n] = relu( sum_k X[m,k]*W[n,k] + bias[n] )
// X,W as bf16 hi/lo planes; products hh + hl + lh. 64x32 tile, BK=64,
// grid (N/32, M/64) = 512 blocks -> 2 blocks/CU. 4 waves, each 32x16.
// ---------------------------------------------------------------------------
template<bool SPLIT_OUT>
__global__ __launch_bounds__(256) void gemm_mfma(
    const unsigned short* __restrict__ Xh, const unsigned short* __restrict__ Xl, int ldx,
    const unsigned short* __restrict__ Wh, const unsigned short* __restrict__ Wl, int ldw,
    const float* __restrict__ bias, int K,
    float* __restrict__ Yf, unsigned short* __restrict__ Yh, unsigned short* __restrict__ Yl,
    int ldy)
{
    __shared__ unsigned short As[2][64][72];   // 18.4 KB
    __shared__ unsigned short Bs[2][32][72];   // 9.2 KB

    const int t = threadIdx.x;
    const int m_base = blockIdx.y * 64;
    const int n_base = blockIdx.x * 32;

    const int trow = t >> 2;          // 0..63  (A rows)
    const int tc   = (t & 3) * 8;     // 0,8,16,24
    const int trB  = t >> 3;          // 0..31  (B rows)
    const int tcB  = (t & 7) * 8;     // 0..56

    const unsigned short* xh_p = Xh + (size_t)(m_base + trow) * ldx + tc;
    const unsigned short* xl_p = Xl + (size_t)(m_base + trow) * ldx + tc;
    const unsigned short* wh_p = Wh + (size_t)(n_base + trB) * ldw + tcB;
    const unsigned short* wl_p = Wl + (size_t)(n_base + trB) * ldw + tcB;

    const int wv   = t >> 6;
    const int lane = t & 63;
    const int wr = (wv >> 1) * 32;    // 0 or 32
    const int wc = (wv & 1) * 16;     // 0 or 16
    const int fr = lane & 15;
    const int fg = (lane >> 4) * 8;

    f32x4 acc0 = {}, acc1 = {};

    for (int k0 = 0; k0 < K; k0 += 64) {
        s16x8 vxh0 = *(const s16x8*)(xh_p + k0);
        s16x8 vxh1 = *(const s16x8*)(xh_p + k0 + 32);
        s16x8 vxl0 = *(const s16x8*)(xl_p + k0);
        s16x8 vxl1 = *(const s16x8*)(xl_p + k0 + 32);
        s16x8 vwh  = *(const s16x8*)(wh_p + k0);
        s16x8 vwl  = *(const s16x8*)(wl_p + k0);
        __syncthreads();
        *(s16x8*)&As[0][trow][tc]      = vxh0;
        *(s16x8*)&As[0][trow][tc + 32] = vxh1;
        *(s16x8*)&As[1][trow][tc]      = vxl0;
        *(s16x8*)&As[1][trow][tc + 32] = vxl1;
        *(s16x8*)&Bs[0][trB][tcB]      = vwh;
        *(s16x8*)&Bs[1][trB][tcB]      = vwl;
        __syncthreads();

        #pragma unroll
        for (int ks = 0; ks < 2; ++ks) {
            const int ko = ks * 32 + fg;
            s16x8 ah0 = *(const s16x8*)&As[0][wr + fr][ko];
            s16x8 ah1 = *(const s16x8*)&As[0][wr + 16 + fr][ko];
            s16x8 al0 = *(const s16x8*)&As[1][wr + fr][ko];
            s16x8 al1 = *(const s16x8*)&As[1][wr + 16 + fr][ko];
            s16x8 bh  = *(const s16x8*)&Bs[0][wc + fr][ko];
            s16x8 bl  = *(const s16x8*)&Bs[1][wc + fr][ko];

            MM(acc0, ah0, bh); MM(acc0, ah0, bl); MM(acc0, al0, bh);
            MM(acc1, ah1, bh); MM(acc1, ah1, bl); MM(acc1, al1, bh);
        }
    }

    const int arow = (lane >> 4) * 4;
    const int col = n_base + wc + fr;
    const float bv = bias[col];
    #pragma unroll
    for (int mf = 0; mf < 2; ++mf) {
        const f32x4 a = mf == 0 ? acc0 : acc1;
        #pragma unroll
        for (int r = 0; r < 4; ++r) {
            const int row = m_base + wr + mf * 16 + arow + r;
            float v = fmaxf(a[r] + bv, 0.f);
            if (SPLIT_OUT) {
                unsigned short h, l;
                split2(v, h, l);
                Yh[(size_t)row * ldy + col] = h;
                Yl[(size_t)row * ldy + col] = l;
            } else {
                Yf[(size_t)row * ldy + col] = v;
            }
        }
    }
}

// ---------------------------------------------------------------------------
// Head: out[b,:] = h2[b,:] @ W3.T + b3
// ---------------------------------------------------------------------------
__global__ __launch_bounds__(256) void head_kernel(
    const float* __restrict__ h2, const float* __restrict__ W3,
    const float* __restrict__ b3, float* __restrict__ out)
{
    const int b = blockIdx.x;
    const int t = threadIdx.x;
    const float* row = h2 + (size_t)b * REP_N;

    float a0 = 0.f, a1 = 0.f, a2 = 0.f, a3 = 0.f;
    for (int k = t; k < REP_N; k += 256) {
        float x = row[k];
        a0 = fmaf(x, W3[k],             a0);
        a1 = fmaf(x, W3[REP_N + k],     a1);
        a2 = fmaf(x, W3[2 * REP_N + k], a2);
        a3 = fmaf(x, W3[3 * REP_N + k], a3);
    }
    #pragma unroll
    for (int off = 32; off > 0; off >>= 1) {
        a0 += __shfl_down(a0, off);
        a1 += __shfl_down(a1, off);
        a2 += __shfl_down(a2, off);
        a3 += __shfl_down(a3, off);
    }
    __shared__ float red[4][4];
    int wid = t >> 6, lane = t & 63;
    if (lane == 0) { red[wid][0] = a0; red[wid][1] = a1; red[wid][2] = a2; red[wid][3] = a3; }
    __syncthreads();
    if (t < 4) {
        out[b * 4 + t] = red[0][t] + red[1][t] + red[2][t] + red[3][t] + b3[t];
    }
}

extern "C" void kernel_launch(void* const* d_in, const int* in_sizes, int n_in,
                              void* d_out, int out_size, void* d_ws, size_t ws_size,
                              hipStream_t stream) {
    const float* p1 = (const float*)d_in[0];
    const float* p2 = (const float*)d_in[1];
    const float* W1 = (const float*)d_in[2];
    const float* b1 = (const float*)d_in[3];
    const float* W2 = (const float*)d_in[4];
    const float* b2 = (const float*)d_in[5];
    const float* W3 = (const float*)d_in[6];
    const float* b3 = (const float*)d_in[7];
    float* out = (float*)d_out;

    char* ws = (char*)d_ws;
    unsigned short* xh  = (unsigned short*)(ws + 0);         // 1.31 MB
    unsigned short* xl  = (unsigned short*)(ws + 1310720);   // 1.31 MB
    unsigned short* w1h = (unsigned short*)(ws + 2621440);   // 1.31 MB
    unsigned short* w1l = (unsigned short*)(ws + 3932160);   // 1.31 MB
    float*          h2  = (float*)(ws + 0);                  // 4.19 MB (reuse after GEMM1)
    unsigned short* h1h = (unsigned short*)(ws + 5242880);   // 2.10 MB
    unsigned short* h1l = (unsigned short*)(ws + 7340032);   // 2.10 MB
    unsigned short* w2h = (unsigned short*)(ws + 9437184);   // 2.10 MB
    unsigned short* w2l = (unsigned short*)(ws + 11534336);  // 2.10 MB

    // Fused corr + weight-prep (interleaved routing, 24.5 KB LDS -> 6 blk/CU)
    corr_prep_kernel<<<4608, 256, 0, stream>>>(
        p1, p2, W1, W2, xh, xl, w1h, w1l, w2h, w2l);

    // GEMM1: h1 = relu(x @ W1g.T + b1), split output planes
    gemm_mfma<true><<<dim3(32, 16), 256, 0, stream>>>(
        xh, xl, KPAD, w1h, w1l, KPAD, b1, KPAD,
        (float*)nullptr, h1h, h1l, REP_N);

    // GEMM2: h2 = relu(h1 @ W2.T + b2), f32 output
    gemm_mfma<false><<<dim3(32, 16), 256, 0, stream>>>(
        h1h, h1l, REP_N, w2h, w2l, REP_N, b2, REP_N,
        h2, (unsigned short*)nullptr, (unsigned short*)nullptr, REP_N);

    head_kernel<<<BATCH, 256, 0, stream>>>(h2, W3, b3, out);
}

// Round 24
// 60.205 us; speedup vs baseline: 1.0111x; 1.0111x over previous
//
#include <hip/hip_runtime.h>

// Problem constants
#define BATCH 1024
#define RR    49        // 7*7 spatial
#define SP    12544     // 256*49 per-batch patch elems; also FLAT
#define KVALID 625      // nonzero correlation outputs per batch
#define KPAD   640      // padded K for GEMM1
#define REP_N  1024

typedef __attribute__((ext_vector_type(4))) float f32x4;
typedef __attribute__((ext_vector_type(8))) short s16x8;   // 8 bf16 (4 VGPRs)

// ---- bf16 split helpers (RNE) ----
__device__ __forceinline__ unsigned short f2bf_rne(float f) {
    unsigned int u = __float_as_uint(f);
    unsigned int r = u + 0x7FFFu + ((u >> 16) & 1u);
    return (unsigned short)(r >> 16);
}
__device__ __forceinline__ float bf2f(unsigned short h) {
    return __uint_as_float(((unsigned int)h) << 16);
}
__device__ __forceinline__ void split2(float v, unsigned short& h, unsigned short& l) {
    h = f2bf_rne(v);
    l = f2bf_rne(v - bf2f(h));
}
// Pack two floats to bf16 pair (verified numerically R4-R23).
__device__ __forceinline__ unsigned int cvtpk_bf16(float a, float b) {
    unsigned int r;
    asm("v_cvt_pk_bf16_f32 %0, %1, %2" : "=v"(r) : "v"(a), "v"(b));
    return r;
}
// Split 8 floats -> hi/lo s16x8 fragments.
__device__ __forceinline__ void cvt8(const float* v, s16x8& hv, s16x8& lv) {
    unsigned int* hp = (unsigned int*)&hv;
    unsigned int* lp = (unsigned int*)&lv;
    #pragma unroll
    for (int i = 0; i < 4; ++i) {
        float v0 = v[2 * i], v1 = v[2 * i + 1];
        unsigned int ph = cvtpk_bf16(v0, v1);
        float h0 = __uint_as_float(ph << 16);
        float h1 = __uint_as_float(ph & 0xFFFF0000u);
        unsigned int pl = cvtpk_bf16(v0 - h0, v1 - h1);
        hp[i] = ph; lp[i] = pl;
    }
}

// Decode index u in [0,25) -> (i, d), i,d in [0,7), i+d even.
__device__ __forceinline__ void dec25(int u, int& i, int& d) {
    int ii = (u >= 4) + (u >= 7) + (u >= 11) + (u >= 14) + (u >= 18) + (u >= 21);
    int cum = (7 * ii + 1) >> 1;
    i = ii;
    d = 2 * (u - cum) + (ii & 1);
}
// Encode (i,d) -> [0,25), inverse of dec25.
__device__ __forceinline__ int enc25(int i, int d) {
    return ((7 * i + 1) >> 1) + ((d - (i & 1)) >> 1);
}

// Compact index a in [0,640) -> flat column into W1's FLAT dim (a>=625 unused).
__device__ __forceinline__ int kflat_of(int a) {
    int ar = a / 25, ac = a % 25;
    int i, dy, j, dx;
    dec25(ar, i, dy);
    dec25(ac, j, dx);
    int pi = (dy + 16 - i) >> 1;
    int pj = (dx + 16 - j) >> 1;
    return (pi * 16 + pj) * 49 + i * 7 + j;
}

#define MM(d, a, b) d = __builtin_amdgcn_mfma_f32_16x16x32_bf16(a, b, d, 0, 0, 0)

// ---------------------------------------------------------------------------
// MEGA kernel: corr (parity Gram, verified R9/R12) + W1/W2 prep fused.
// Block routing (interleaved): bid<2048 even -> corr batch bid/2; odd ->
// W1-prep bid/2; bid>=2048 -> prep 1024+(bid-2048).
// corr: 8 half-chunks (32 ch) double-buffered via global_load_lds width=16,
// counted vmcnt (T4). 28 KB LDS -> 5 blocks/CU (R21/R22 best, held).
// ---------------------------------------------------------------------------
__global__ __launch_bounds__(256) void corr_prep_kernel(
    const float* __restrict__ p1, const float* __restrict__ p2,
    const float* __restrict__ W1, const float* __restrict__ W2,
    unsigned short* __restrict__ xh, unsigned short* __restrict__ xl,
    unsigned short* __restrict__ w1h, unsigned short* __restrict__ w1l,
    unsigned short* __restrict__ w2h, unsigned short* __restrict__ w2l)
{
    __shared__ float4 Tb[2][2][448];       // [buf][tensor][7*64] = 28 KB

    const int bid = blockIdx.x;
    const int t   = threadIdx.x;

    bool isCorr = false;
    int cid = 0, pid = 0;
    if (bid < 2048) {
        if ((bid & 1) == 0) { isCorr = true; cid = bid >> 1; }
        else                { pid = bid >> 1; }
    } else {
        pid = 1024 + (bid - 2048);
    }

    if (!isCorr) {
        // ---- weight prep branch (block-uniform) ----
        if (pid < 2560) {
            int idx = pid * 256 + t;             // over REP_N*KPAD
            int n = idx / KPAD, a = idx - n * KPAD;
            float v = 0.f;
            if (a < KVALID) v = W1[(size_t)n * SP + kflat_of(a)];
            unsigned short h, l;
            split2(v, h, l);
            w1h[idx] = h; w1l[idx] = l;
        } else {
            int idx = ((pid - 2560) * 256 + t) * 4;   // over REP_N*REP_N
            float4 v = *(const float4*)&W2[idx];
            unsigned short h0, l0, h1, l1, h2, l2, h3, l3;
            split2(v.x, h0, l0); split2(v.y, h1, l1);
            split2(v.z, h2, l2); split2(v.w, h3, l3);
            *(ushort4*)&w2h[idx] = make_ushort4(h0, h1, h2, h3);
            *(ushort4*)&w2l[idx] = make_ushort4(l0, l1, l2, l3);
        }
        return;
    }

    // ---- corr branch ----
    const float* P1 = p1 + (size_t)cid * SP;
    const float* P2 = p2 + (size_t)cid * SP;

    const int wv   = t >> 6;
    const int lane = t & 63;
    const int fr   = lane & 15;        // class-pos index (A row / B col)
    const int fg   = (lane >> 4) * 8;  // k-offset within 32-row tile

    // parity-class geometry
    const int ci = wv >> 1, cj = wv & 1;
    const int nj = 4 - cj;
    const int clsN = (4 - ci) * nj;          // 16 / 12 / 12 / 9
    const int pr = (fr < clsN) ? fr : 0;
    const int sPos = (2 * (pr / nj) + ci) * 7 + (2 * (pr % nj) + cj);

    // staging role: waves 0,1 -> p1; waves 2,3 -> p2. Half-chunk = 32ch*49
    // = 1568 floats = 392 float4. Even staging waves issue 4 loads (bq 0..3,
    // dest [0,256)); odd waves issue 3 (bq 4..6, dest [256,448); bq6's
    // src-clamped lanes land in pad [392,448)). vmcnt waits are PER-WAVE.
    const float* PS = (wv < 2) ? P1 : P2;
    const int tens  = wv >> 1;
    const int start = (wv & 1) * 4;          // bq range [0,4) or [4,7)
    const int nb    = (wv & 1) ? 3 : 4;      // loads per stage (wave-uniform)

    #define STAGE(buf, hc)                                                     \
        do {                                                                   \
            const int off_ = (hc) * 1568;                                      \
            float4* T_ = &Tb[(buf)][tens][0];                                  \
            _Pragma("unroll")                                                  \
            for (int j_ = 0; j_ < 4; ++j_) {                                   \
                if (j_ < nb) {                                                 \
                    const int bq_  = start + j_;                               \
                    const int src_ = min(bq_ * 64 + lane, 391);                \
                    __builtin_amdgcn_global_load_lds(                          \
                        (const __attribute__((address_space(1))) unsigned int*)\
                            (PS + off_ + src_ * 4),                            \
                        (__attribute__((address_space(3))) unsigned int*)      \
                            (T_ + bq_ * 64),                                   \
                        16, 0, 0);                                             \
                }                                                              \
            }                                                                  \
        } while (0)

    STAGE(0, 0);   // prologue: 2 stages in flight (8 or 6 loads per wave)
    STAGE(1, 1);

    f32x4 acc = {};
    #pragma unroll
    for (int hc = 0; hc < 8; ++hc) {
        // Wait ONLY for the current stage's loads (oldest in the queue);
        // the next stage's loads remain outstanding across the barrier.
        if (hc < 7) {
            if (wv & 1) asm volatile("s_waitcnt vmcnt(3)" ::: "memory");
            else        asm volatile("s_waitcnt vmcnt(4)" ::: "memory");
        } else {
            asm volatile("s_waitcnt vmcnt(0)" ::: "memory");
        }
        __builtin_amdgcn_s_barrier();          // all waves' current loads landed
        __builtin_amdgcn_sched_barrier(0);     // pin: no ds_read hoisted above

        const int cur = hc & 1;
        const float* Tf1 = (const float*)&Tb[cur][0][0];
        const float* Tf2 = (const float*)&Tb[cur][1][0];
        const int kb = fg * RR + sPos;
        float av[8], bv[8];
        #pragma unroll
        for (int i = 0; i < 8; ++i) {
            av[i] = Tf1[kb + i * RR];
            bv[i] = Tf2[kb + i * RR];
        }
        s16x8 ah, al, bh, bl;
        cvt8(av, ah, al);
        cvt8(bv, bh, bl);
        MM(acc, ah, bh);
        MM(acc, ah, bl);
        MM(acc, al, bh);

        __builtin_amdgcn_sched_barrier(0);
        __builtin_amdgcn_s_barrier();          // all waves done reading buf[cur]
        if (hc < 6) STAGE(cur, hc + 2);        // refill the buffer just freed
    }
    #undef STAGE

    // Epilogue (verified R9 mapping): direct scattered global stores.
    // C/D layout: col = lane&15, row = 4*(lane>>4)+r.
    unsigned short* rh = xh + (size_t)cid * KPAD;
    unsigned short* rl = xl + (size_t)cid * KPAD;
    if (t < KPAD - KVALID) {                   // zero the 15-element pad tail
        rh[KVALID + t] = 0;
        rl[KVALID + t] = 0;
    }
    const int arow = (lane >> 4) * 4;
    if (fr < clsN) {
        const int dy = 2 * (fr / nj) + ci;
        const int dx = 2 * (fr % nj) + cj;
        #pragma unroll
        for (int r = 0; r < 4; ++r) {
            const int rowp = arow + r;
            if (rowp < clsN) {
                const int i1 = 2 * (rowp / nj) + ci;
                const int j1 = 2 * (rowp % nj) + cj;
                const int aidx = enc25(i1, dy) * 25 + enc25(j1, dx);
                unsigned short hh, ll;
                split2(acc[r], hh, ll);
                rh[aidx] = hh; rl[aidx] = ll;
            }
        }
    }
}

// ---------------------------------------------------------------------------
// MFMA GEMM: Y[m,n] = relu( sum_k X[m,k]*W[n,k] + bias[n] )
// X,W as bf16 hi/lo planes; products hh + hl + lh. 64x32 tile, BK=64,
// grid (N/32, M/64) = 512 blocks -> 2 blocks/CU. 4 waves, each 32x16.
// ---------------------------------------------------------------------------
template<bool SPLIT_OUT>
__global__ __launch_bounds__(256) void gemm_mfma(
    const unsigned short* __restrict__ Xh, const unsigned short* __restrict__ Xl, int ldx,
    const unsigned short* __restrict__ Wh, const unsigned short* __restrict__ Wl, int ldw,
    const float* __restrict__ bias, int K,
    float* __restrict__ Yf, unsigned short* __restrict__ Yh, unsigned short* __restrict__ Yl,
    int ldy)
{
    __shared__ unsigned short As[2][64][72];   // 18.4 KB
    __shared__ unsigned short Bs[2][32][72];   // 9.2 KB

    const int t = threadIdx.x;
    const int m_base = blockIdx.y * 64;
    const int n_base = blockIdx.x * 32;

    const int trow = t >> 2;          // 0..63  (A rows)
    const int tc   = (t & 3) * 8;     // 0,8,16,24
    const int trB  = t >> 3;          // 0..31  (B rows)
    const int tcB  = (t & 7) * 8;     // 0..56

    const unsigned short* xh_p = Xh + (size_t)(m_base + trow) * ldx + tc;
    const unsigned short* xl_p = Xl + (size_t)(m_base + trow) * ldx + tc;
    const unsigned short* wh_p = Wh + (size_t)(n_base + trB) * ldw + tcB;
    const unsigned short* wl_p = Wl + (size_t)(n_base + trB) * ldw + tcB;

    const int wv   = t >> 6;
    const int lane = t & 63;
    const int wr = (wv >> 1) * 32;    // 0 or 32
    const int wc = (wv & 1) * 16;     // 0 or 16
    const int fr = lane & 15;
    const int fg = (lane >> 4) * 8;

    f32x4 acc0 = {}, acc1 = {};

    for (int k0 = 0; k0 < K; k0 += 64) {
        s16x8 vxh0 = *(const s16x8*)(xh_p + k0);
        s16x8 vxh1 = *(const s16x8*)(xh_p + k0 + 32);
        s16x8 vxl0 = *(const s16x8*)(xl_p + k0);
        s16x8 vxl1 = *(const s16x8*)(xl_p + k0 + 32);
        s16x8 vwh  = *(const s16x8*)(wh_p + k0);
        s16x8 vwl  = *(const s16x8*)(wl_p + k0);
        __syncthreads();
        *(s16x8*)&As[0][trow][tc]      = vxh0;
        *(s16x8*)&As[0][trow][tc + 32] = vxh1;
        *(s16x8*)&As[1][trow][tc]      = vxl0;
        *(s16x8*)&As[1][trow][tc + 32] = vxl1;
        *(s16x8*)&Bs[0][trB][tcB]      = vwh;
        *(s16x8*)&Bs[1][trB][tcB]      = vwl;
        __syncthreads();

        #pragma unroll
        for (int ks = 0; ks < 2; ++ks) {
            const int ko = ks * 32 + fg;
            s16x8 ah0 = *(const s16x8*)&As[0][wr + fr][ko];
            s16x8 ah1 = *(const s16x8*)&As[0][wr + 16 + fr][ko];
            s16x8 al0 = *(const s16x8*)&As[1][wr + fr][ko];
            s16x8 al1 = *(const s16x8*)&As[1][wr + 16 + fr][ko];
            s16x8 bh  = *(const s16x8*)&Bs[0][wc + fr][ko];
            s16x8 bl  = *(const s16x8*)&Bs[1][wc + fr][ko];

            MM(acc0, ah0, bh); MM(acc0, ah0, bl); MM(acc0, al0, bh);
            MM(acc1, ah1, bh); MM(acc1, ah1, bl); MM(acc1, al1, bh);
        }
    }

    const int arow = (lane >> 4) * 4;
    const int col = n_base + wc + fr;
    const float bv = bias[col];
    #pragma unroll
    for (int mf = 0; mf < 2; ++mf) {
        const f32x4 a = mf == 0 ? acc0 : acc1;
        #pragma unroll
        for (int r = 0; r < 4; ++r) {
            const int row = m_base + wr + mf * 16 + arow + r;
            float v = fmaxf(a[r] + bv, 0.f);
            if (SPLIT_OUT) {
                unsigned short h, l;
                split2(v, h, l);
                Yh[(size_t)row * ldy + col] = h;
                Yl[(size_t)row * ldy + col] = l;
            } else {
                Yf[(size_t)row * ldy + col] = v;
            }
        }
    }
}

// ---------------------------------------------------------------------------
// Head: out[b,:] = h2[b,:] @ W3.T + b3
// ---------------------------------------------------------------------------
__global__ __launch_bounds__(256) void head_kernel(
    const float* __restrict__ h2, const float* __restrict__ W3,
    const float* __restrict__ b3, float* __restrict__ out)
{
    const int b = blockIdx.x;
    const int t = threadIdx.x;
    const float* row = h2 + (size_t)b * REP_N;

    float a0 = 0.f, a1 = 0.f, a2 = 0.f, a3 = 0.f;
    for (int k = t; k < REP_N; k += 256) {
        float x = row[k];
        a0 = fmaf(x, W3[k],             a0);
        a1 = fmaf(x, W3[REP_N + k],     a1);
        a2 = fmaf(x, W3[2 * REP_N + k], a2);
        a3 = fmaf(x, W3[3 * REP_N + k], a3);
    }
    #pragma unroll
    for (int off = 32; off > 0; off >>= 1) {
        a0 += __shfl_down(a0, off);
        a1 += __shfl_down(a1, off);
        a2 += __shfl_down(a2, off);
        a3 += __shfl_down(a3, off);
    }
    __shared__ float red[4][4];
    int wid = t >> 6, lane = t & 63;
    if (lane == 0) { red[wid][0] = a0; red[wid][1] = a1; red[wid][2] = a2; red[wid][3] = a3; }
    __syncthreads();
    if (t < 4) {
        out[b * 4 + t] = red[0][t] + red[1][t] + red[2][t] + red[3][t] + b3[t];
    }
}

extern "C" void kernel_launch(void* const* d_in, const int* in_sizes, int n_in,
                              void* d_out, int out_size, void* d_ws, size_t ws_size,
                              hipStream_t stream) {
    const float* p1 = (const float*)d_in[0];
    const float* p2 = (const float*)d_in[1];
    const float* W1 = (const float*)d_in[2];
    const float* b1 = (const float*)d_in[3];
    const float* W2 = (const float*)d_in[4];
    const float* b2 = (const float*)d_in[5];
    const float* W3 = (const float*)d_in[6];
    const float* b3 = (const float*)d_in[7];
    float* out = (float*)d_out;

    char* ws = (char*)d_ws;
    unsigned short* xh  = (unsigned short*)(ws + 0);         // 1.31 MB
    unsigned short* xl  = (unsigned short*)(ws + 1310720);   // 1.31 MB
    unsigned short* w1h = (unsigned short*)(ws + 2621440);   // 1.31 MB
    unsigned short* w1l = (unsigned short*)(ws + 3932160);   // 1.31 MB
    float*          h2  = (float*)(ws + 0);                  // 4.19 MB (reuse after GEMM1)
    unsigned short* h1h = (unsigned short*)(ws + 5242880);   // 2.10 MB
    unsigned short* h1l = (unsigned short*)(ws + 7340032);   // 2.10 MB
    unsigned short* w2h = (unsigned short*)(ws + 9437184);   // 2.10 MB
    unsigned short* w2l = (unsigned short*)(ws + 11534336);  // 2.10 MB

    // Fused corr + weight-prep (interleaved routing, 28 KB LDS -> 5 blk/CU)
    corr_prep_kernel<<<4608, 256, 0, stream>>>(
        p1, p2, W1, W2, xh, xl, w1h, w1l, w2h, w2l);

    // GEMM1: h1 = relu(x @ W1g.T + b1), split output planes
    gemm_mfma<true><<<dim3(32, 16), 256, 0, stream>>>(
        xh, xl, KPAD, w1h, w1l, KPAD, b1, KPAD,
        (float*)nullptr, h1h, h1l, REP_N);

    // GEMM2: h2 = relu(h1 @ W2.T + b2), f32 output
    gemm_mfma<false><<<dim3(32, 16), 256, 0, stream>>>(
        h1h, h1l, REP_N, w2h, w2l, REP_N, b2, REP_N,
        h2, (unsigned short*)nullptr, (unsigned short*)nullptr, REP_N);

    head_kernel<<<BATCH, 256, 0, stream>>>(h2, W3, b3, out);
}